// Round 1
// baseline (62.711 us; speedup 1.0000x reference)
//
#include <hip/hip_runtime.h>

// Shapes fixed by reference setup_inputs(): (B=16, NI=11, T=65536), LST=64.
#define B_  16
#define NI  11
#define T_  65536
#define LST 64

__device__ __forceinline__ void ce_desc(float& a, float& b) {
    float mx = fmaxf(a, b);
    float mn = fminf(a, b);
    a = mx; b = mn;
}

__global__ __launch_bounds__(256) void fused_sparsemax_kernel(
        const float* __restrict__ in, float* __restrict__ out) {
    const int lane = threadIdx.x & 63;
    const int wid  = threadIdx.x >> 6;
    const int tile = blockIdx.x * 4 + wid;      // 16*1024 = 16384 tiles total
    const int b    = tile >> 10;                // T_/LST = 1024 blocks per batch
    const int jb   = tile & 1023;
    const int t    = jb * LST + lane;

    const size_t base = (size_t)b * NI * T_ + (size_t)t;
    const float* px = in + base;
    float* po = out + base;

    // ---- load: 11 coalesced loads (one per instrument row) ----
    float z[NI];
#pragma unroll
    for (int i = 0; i < NI; ++i) z[i] = px[(size_t)i * T_];

    // ---- instrument sparsemax: per lane over the 11 values ----
    float s[NI];
#pragma unroll
    for (int i = 0; i < NI; ++i) s[i] = z[i];
    // odd-even transposition sort, descending, NI passes (fully unrolled)
#pragma unroll
    for (int p = 0; p < NI; ++p) {
#pragma unroll
        for (int k = (p & 1); k + 1 < NI; k += 2) ce_desc(s[k], s[k + 1]);
    }
    // k_z = count of support (matches reference's sum(support))
    int kz = 0;
    {
        float cum = 0.0f;
#pragma unroll
        for (int k = 1; k <= NI; ++k) {
            cum += s[k - 1];
            kz += (1.0f + (float)k * s[k - 1] > cum) ? 1 : 0;
        }
    }
    float tau_sum = 0.0f;
    {
        float cum = 0.0f;
#pragma unroll
        for (int k = 1; k <= NI; ++k) {
            cum += s[k - 1];
            if (k == kz) tau_sum = cum;
        }
    }
    const float tau_inst = (tau_sum - 1.0f) / (float)kz;

    // ---- time sparsemax per instrument: 64-lane cross-wave ----
#pragma unroll
    for (int i = 0; i < NI; ++i) {
        float v = z[i];
        // bitonic sort, descending across 64 lanes
#pragma unroll
        for (int k = 2; k <= 64; k <<= 1) {
#pragma unroll
            for (int j = k >> 1; j >= 1; j >>= 1) {
                float o = __shfl_xor(v, j, 64);
                bool asc   = (lane & k) != 0;   // this block sorts ascending
                bool lower = (lane & j) == 0;
                v = (asc == lower) ? fminf(v, o) : fmaxf(v, o);
            }
        }
        // inclusive prefix sum of sorted values
        float c = v;
#pragma unroll
        for (int off = 1; off < 64; off <<= 1) {
            float o = __shfl_up(c, off, 64);
            if (lane >= off) c += o;
        }
        // support + tau
        unsigned long long m = __ballot(1.0f + (float)(lane + 1) * v > c);
        int k_z = __popcll(m);                   // >= 1 always (k=1: 1+z0 > z0)
        float ts = __shfl(c, k_z - 1, 64);
        float tau_t = (ts - 1.0f) / (float)k_z;

        float oi = fmaxf(z[i] - tau_t, 0.0f) * fmaxf(z[i] - tau_inst, 0.0f);
        po[(size_t)i * T_] = oi;
    }
}

extern "C" void kernel_launch(void* const* d_in, const int* in_sizes, int n_in,
                              void* d_out, int out_size, void* d_ws, size_t ws_size,
                              hipStream_t stream) {
    const float* in = (const float*)d_in[0];
    float* out = (float*)d_out;
    // 16384 wave-tiles, 4 waves per 256-thread block -> 4096 blocks
    dim3 grid(4096), block(256);
    hipLaunchKernelGGL(fused_sparsemax_kernel, grid, block, 0, stream, in, out);
}

// Round 2
// 37.768 us; speedup vs baseline: 1.6604x; 1.6604x over previous
//
#include <hip/hip_runtime.h>

// Shapes fixed by reference setup_inputs(): (B=16, NI=11, T=65536), LST=64.
#define B_   16
#define NI   11
#define T_   65536
#define LST  64
#define NBLK (T_ / LST)   // 1024

__device__ __forceinline__ void ce_desc(float& a, float& b) {
    float mx = fmaxf(a, b);
    float mn = fminf(a, b);
    a = mx; b = mn;
}

// ---------------------------------------------------------------------------
// Kernel 1: instrument-axis sparsemax threshold tau_inst(b, t).
// One thread per (b, t). 11 strided (coalesced along t) loads, per-lane
// register sorting network (d=11), write tau to workspace. VALU-only.
// ---------------------------------------------------------------------------
__global__ __launch_bounds__(256) void tau_inst_kernel(
        const float* __restrict__ in, float* __restrict__ tau_out) {
    const int idx = blockIdx.x * 256 + threadIdx.x;   // idx = b*T + t
    const int b = idx >> 16;                          // T = 65536
    const int t = idx & (T_ - 1);

    const float* px = in + (size_t)b * NI * T_ + (size_t)t;
    float s[NI];
#pragma unroll
    for (int i = 0; i < NI; ++i) s[i] = px[(size_t)i * T_];

    // odd-even transposition sort, descending (fully unrolled, VALU only)
#pragma unroll
    for (int p = 0; p < NI; ++p) {
#pragma unroll
        for (int k = (p & 1); k + 1 < NI; k += 2) ce_desc(s[k], s[k + 1]);
    }
    int kz = 0;
    {
        float cum = 0.0f;
#pragma unroll
        for (int k = 1; k <= NI; ++k) {
            cum += s[k - 1];
            kz += (1.0f + (float)k * s[k - 1] > cum) ? 1 : 0;
        }
    }
    float tau_sum = 0.0f;
    {
        float cum = 0.0f;
#pragma unroll
        for (int k = 1; k <= NI; ++k) {
            cum += s[k - 1];
            if (k == kz) tau_sum = cum;
        }
    }
    tau_out[idx] = (tau_sum - 1.0f) / (float)kz;
}

// ---------------------------------------------------------------------------
// Kernel 2: time-axis sparsemax (Michelot/Newton, sort-free) + final multiply.
// 4-lane group owns one (row=b*11+i, block jb) task: 16 elements/lane in
// registers. Newton step = per-lane masked sums (VALU) + 2 shfl_xor stages.
// ---------------------------------------------------------------------------
__global__ __launch_bounds__(256) void tau_time_mul_kernel(
        const float* __restrict__ in, const float* __restrict__ tau_inst,
        float* __restrict__ out) {
    const int tid  = threadIdx.x;
    const int q    = tid & 3;                       // sub-lane within group
    const int task = blockIdx.x * 64 + (tid >> 2);  // 64 groups per block

    const int row = task >> 10;                     // row = b*NI + i
    const int jb  = task & (NBLK - 1);
    const int b   = row / NI;

    const size_t ibase = (size_t)row * T_ + (size_t)jb * LST + (size_t)q * 16;
    const size_t tbase = (size_t)b * T_ + (size_t)jb * LST + (size_t)q * 16;

    // ---- load 16 elements (4x float4, coalesced across the wave) ----
    const float4* pz = reinterpret_cast<const float4*>(in + ibase);
    float4 a0 = pz[0], a1 = pz[1], a2 = pz[2], a3 = pz[3];
    float z[16] = {a0.x, a0.y, a0.z, a0.w, a1.x, a1.y, a1.z, a1.w,
                   a2.x, a2.y, a2.z, a2.w, a3.x, a3.y, a3.z, a3.w};

    // ---- Michelot / Newton: tau s.t. sum(relu(z - tau)) = 1 ----
    float s_all = 0.0f;
#pragma unroll
    for (int r = 0; r < 16; ++r) s_all += z[r];
    s_all += __shfl_xor(s_all, 1, 64);
    s_all += __shfl_xor(s_all, 2, 64);
    float tau = (s_all - 1.0f) * (1.0f / 64.0f);
    int prev = 64;

    for (int it = 0; it < 48; ++it) {
        float sp = 0.0f, cp = 0.0f;
#pragma unroll
        for (int r = 0; r < 16; ++r) {
            bool a = z[r] > tau;
            sp += a ? z[r] : 0.0f;
            cp += a ? 1.0f : 0.0f;
        }
        sp += __shfl_xor(sp, 1, 64);
        sp += __shfl_xor(sp, 2, 64);
        cp += __shfl_xor(cp, 1, 64);
        cp += __shfl_xor(cp, 2, 64);
        int cnt = (int)cp;
        bool changed = (cnt != prev);
        if (!__any(changed)) break;   // all groups in wave converged
        prev = cnt;
        tau  = (sp - 1.0f) / cp;      // cp >= 1 always (max element stays)
    }

    // ---- load tau_inst for this lane's 16 time positions ----
    const float4* pt = reinterpret_cast<const float4*>(tau_inst + tbase);
    float4 t0 = pt[0], t1 = pt[1], t2 = pt[2], t3 = pt[3];
    float ti[16] = {t0.x, t0.y, t0.z, t0.w, t1.x, t1.y, t1.z, t1.w,
                    t2.x, t2.y, t2.z, t2.w, t3.x, t3.y, t3.z, t3.w};

    // ---- final: relu(z - tau_time) * relu(z - tau_inst), store ----
    float o[16];
#pragma unroll
    for (int r = 0; r < 16; ++r)
        o[r] = fmaxf(z[r] - tau, 0.0f) * fmaxf(z[r] - ti[r], 0.0f);

    float4* po = reinterpret_cast<float4*>(out + ibase);
    po[0] = make_float4(o[0],  o[1],  o[2],  o[3]);
    po[1] = make_float4(o[4],  o[5],  o[6],  o[7]);
    po[2] = make_float4(o[8],  o[9],  o[10], o[11]);
    po[3] = make_float4(o[12], o[13], o[14], o[15]);
}

extern "C" void kernel_launch(void* const* d_in, const int* in_sizes, int n_in,
                              void* d_out, int out_size, void* d_ws, size_t ws_size,
                              hipStream_t stream) {
    const float* in = (const float*)d_in[0];
    float* out = (float*)d_out;
    float* tau_ws = (float*)d_ws;   // needs B_*T_*4 = 4 MB

    // Kernel 1: 16*65536 threads -> 4096 blocks of 256
    hipLaunchKernelGGL(tau_inst_kernel, dim3(4096), dim3(256), 0, stream,
                       in, tau_ws);
    // Kernel 2: 16*11*1024 tasks, 64 tasks per 256-thread block -> 2816 blocks
    hipLaunchKernelGGL(tau_time_mul_kernel, dim3(2816), dim3(256), 0, stream,
                       in, tau_ws, out);
}

// Round 3
// 28.485 us; speedup vs baseline: 2.2016x; 1.3259x over previous
//
#include <hip/hip_runtime.h>

// Shapes fixed by reference setup_inputs(): (B=16, NI=11, T=65536), LST=64.
#define B_   16
#define NI   11
#define T_   65536
#define LST  64
#define NBLK (T_ / LST)     // 1024
#define ROWS 66             // LDS row stride (floats): breaks bank alignment

__device__ __forceinline__ void ce_desc(float& a, float& b) {
    float mx = fmaxf(a, b);
    float mn = fminf(a, b);
    a = mx; b = mn;
}

// One wave per (b, jb) tile of 11 instruments x 64 timesteps.
// Fully fused: read input once, write output once, no global scratch.
__global__ __launch_bounds__(256) void fused_sparsemax_kernel(
        const float* __restrict__ in, float* __restrict__ out) {
    __shared__ float ldsz[4][NI * ROWS];   // per-wave z tile, transposed access
    __shared__ float ldst[4][16];          // per-wave tau_time[11]

    const int lane = threadIdx.x & 63;
    const int wid  = threadIdx.x >> 6;
    const int tile = blockIdx.x * 4 + wid;         // 16384 tiles
    const int b    = tile >> 10;
    const int jb   = tile & (NBLK - 1);

    const size_t base = (size_t)b * NI * T_ + (size_t)jb * LST + (size_t)lane;
    const float* px = in + base;
    float* po = out + base;

    // ---- load: 11 coalesced 4B loads (one per instrument row) ----
    float z[NI];
#pragma unroll
    for (int i = 0; i < NI; ++i) z[i] = px[(size_t)i * T_];

    // ---- instrument sparsemax (d=11) per lane: exact sort-based tau ----
    float s[NI];
#pragma unroll
    for (int i = 0; i < NI; ++i) s[i] = z[i];
#pragma unroll
    for (int p = 0; p < NI; ++p) {
#pragma unroll
        for (int k = (p & 1); k + 1 < NI; k += 2) ce_desc(s[k], s[k + 1]);
    }
    int kz = 0;
    {
        float cum = 0.0f;
#pragma unroll
        for (int k = 1; k <= NI; ++k) {
            cum += s[k - 1];
            kz += (1.0f + (float)k * s[k - 1] > cum) ? 1 : 0;
        }
    }
    float tau_sum = 0.0f;
    {
        float cum = 0.0f;
#pragma unroll
        for (int k = 1; k <= NI; ++k) {
            cum += s[k - 1];
            if (k == kz) tau_sum = cum;
        }
    }
    const float tau_inst = (tau_sum - 1.0f) / (float)kz;

    // ---- stage tile to LDS for the transposed (row-wise) pass ----
#pragma unroll
    for (int i = 0; i < NI; ++i) ldsz[wid][i * ROWS + lane] = z[i];

    // ---- time sparsemax: 4-lane group g owns instrument row g (g<11).
    //      16 elements/lane; Michelot iteration = 48 VALU + 4 shuffles. ----
    const int g   = lane >> 2;
    const int q   = lane & 3;
    const int row = (g < NI) ? g : (g - NI);      // idle groups duplicate rows

    float y[16];
#pragma unroll
    for (int r = 0; r < 16; ++r) y[r] = ldsz[wid][row * ROWS + q * 16 + r];

    float s_all = 0.0f;
#pragma unroll
    for (int r = 0; r < 16; ++r) s_all += y[r];
    s_all += __shfl_xor(s_all, 1, 64);
    s_all += __shfl_xor(s_all, 2, 64);
    float tau = (s_all - 1.0f) * (1.0f / 64.0f);
    int prev = 64;

    for (int it = 0; it < 64; ++it) {
        float sp = 0.0f, cp = 0.0f;
#pragma unroll
        for (int r = 0; r < 16; ++r) {
            bool a = y[r] > tau;
            sp += a ? y[r] : 0.0f;
            cp += a ? 1.0f : 0.0f;
        }
        sp += __shfl_xor(sp, 1, 64);
        sp += __shfl_xor(sp, 2, 64);
        cp += __shfl_xor(cp, 1, 64);
        cp += __shfl_xor(cp, 2, 64);
        int cnt = (int)cp;
        bool changed = (cnt != prev);
        if (!__any(changed)) break;   // support stable for every group in wave
        prev = cnt;
        tau  = (sp - 1.0f) / cp;      // cp >= 1 always (max element survives)
    }

    if (g < NI && q == 0) ldst[wid][g] = tau;

    // ---- epilogue: out = relu(z - tau_time) * relu(z - tau_inst) ----
    float tt[NI];
#pragma unroll
    for (int i = 0; i < NI; ++i) tt[i] = ldst[wid][i];   // broadcast reads

#pragma unroll
    for (int i = 0; i < NI; ++i) {
        float oi = fmaxf(z[i] - tt[i], 0.0f) * fmaxf(z[i] - tau_inst, 0.0f);
        po[(size_t)i * T_] = oi;
    }
}

extern "C" void kernel_launch(void* const* d_in, const int* in_sizes, int n_in,
                              void* d_out, int out_size, void* d_ws, size_t ws_size,
                              hipStream_t stream) {
    const float* in = (const float*)d_in[0];
    float* out = (float*)d_out;
    // 16384 wave-tiles, 4 waves per 256-thread block -> 4096 blocks
    hipLaunchKernelGGL(fused_sparsemax_kernel, dim3(4096), dim3(256), 0, stream,
                       in, out);
}

// Round 4
// 27.566 us; speedup vs baseline: 2.2749x; 1.0333x over previous
//
#include <hip/hip_runtime.h>

// Shapes fixed by reference setup_inputs(): (B=16, NI=11, T=65536), LST=64.
#define B_   16
#define NI   11
#define T_   65536
#define LST  64
#define NBLK (T_ / LST)     // 1024
#define ROWP 68             // LDS row stride (floats): 272B, 16B-aligned

__device__ __forceinline__ float frcp(float x) { return __builtin_amdgcn_rcpf(x); }

// One wave per (b, jb) tile of 11 instruments x 64 timesteps. Fully fused.
// Sparsemax taus via max-init Michelot: tau* >= max-1, so starting the
// support at {z > max-1} (tiny for Gaussian data) converges in ~3 iters,
// monotonically, exactly (stop when support count stable).
__global__ __launch_bounds__(256) void fused_sparsemax_kernel(
        const float* __restrict__ in, float* __restrict__ out) {
    __shared__ float ldsz[4][NI * ROWP];   // z tile, row-major [inst][t]
    __shared__ float ldsti[4][64];         // tau_inst[t] transpose buffer

    const int lane = threadIdx.x & 63;
    const int wid  = threadIdx.x >> 6;
    const int tile = blockIdx.x * 4 + wid;          // 16384 tiles
    const int b    = tile >> 10;
    const int jb   = tile & (NBLK - 1);

    const float* px = in + (size_t)b * NI * T_ + (size_t)jb * LST + (size_t)lane;

    // ---- load: 11 coalesced 4B loads (one per instrument row) ----
    float z[NI];
#pragma unroll
    for (int i = 0; i < NI; ++i) z[i] = px[(size_t)i * T_];

    // stage tile to LDS early (latency hides under tau_inst compute)
#pragma unroll
    for (int i = 0; i < NI; ++i) ldsz[wid][i * ROWP + lane] = z[i];

    // ---- instrument tau: per-lane max-init Michelot over d=11 ----
    float mx = z[0];
#pragma unroll
    for (int i = 1; i < NI; ++i) mx = fmaxf(mx, z[i]);
    float tau_i = mx - 1.0f;
    float prevc = 0.0f;
    for (int it = 0; it < NI + 2; ++it) {            // worst case: 11 shrinks
        float sp = 0.0f, cp = 0.0f;
#pragma unroll
        for (int i = 0; i < NI; ++i) {
            bool a = z[i] > tau_i;
            sp += a ? z[i] : 0.0f;
            cp += a ? 1.0f : 0.0f;
        }
        bool changed = (cp != prevc);
        if (!__any(changed)) break;                  // support stable -> exact
        prevc = cp;
        tau_i = (sp - 1.0f) * frcp(cp);
    }
    ldsti[wid][lane] = tau_i;                        // lane == t within block

    // ---- time tau: 4-lane group g owns instrument row g (g<11) ----
    const int g   = lane >> 2;
    const int q   = lane & 3;
    const int row = (g < NI) ? g : (g - NI);         // spare groups duplicate

    float y[16];
#pragma unroll
    for (int r = 0; r < 16; ++r) y[r] = ldsz[wid][row * ROWP + q * 16 + r];

    float m = y[0];
#pragma unroll
    for (int r = 1; r < 16; ++r) m = fmaxf(m, y[r]);
    m = fmaxf(m, __shfl_xor(m, 1, 64));
    m = fmaxf(m, __shfl_xor(m, 2, 64));
    float tau = m - 1.0f;
    float prev = 0.0f;
    for (int it = 0; it < LST + 2; ++it) {           // worst case: 64 shrinks
        float sp = 0.0f, cp = 0.0f;
#pragma unroll
        for (int r = 0; r < 16; ++r) {
            bool a = y[r] > tau;
            sp += a ? y[r] : 0.0f;
            cp += a ? 1.0f : 0.0f;
        }
        sp += __shfl_xor(sp, 1, 64);
        sp += __shfl_xor(sp, 2, 64);
        cp += __shfl_xor(cp, 1, 64);
        cp += __shfl_xor(cp, 2, 64);
        bool changed = (cp != prev);
        if (!__any(changed)) break;                  // all groups stable
        prev = cp;
        tau = (sp - 1.0f) * frcp(cp);
    }

    // ---- epilogue in group layout: float4 stores, tau_inst via LDS ----
    if (g < NI) {
        float ti[16];
#pragma unroll
        for (int r = 0; r < 16; ++r) ti[r] = ldsti[wid][q * 16 + r];

        float* po = out + (size_t)b * NI * T_ + (size_t)g * T_
                        + (size_t)jb * LST + (size_t)q * 16;
        float4* po4 = reinterpret_cast<float4*>(po);
#pragma unroll
        for (int v = 0; v < 4; ++v) {
            float4 o;
            o.x = fmaxf(y[4*v+0] - tau, 0.0f) * fmaxf(y[4*v+0] - ti[4*v+0], 0.0f);
            o.y = fmaxf(y[4*v+1] - tau, 0.0f) * fmaxf(y[4*v+1] - ti[4*v+1], 0.0f);
            o.z = fmaxf(y[4*v+2] - tau, 0.0f) * fmaxf(y[4*v+2] - ti[4*v+2], 0.0f);
            o.w = fmaxf(y[4*v+3] - tau, 0.0f) * fmaxf(y[4*v+3] - ti[4*v+3], 0.0f);
            po4[v] = o;
        }
    }
}

extern "C" void kernel_launch(void* const* d_in, const int* in_sizes, int n_in,
                              void* d_out, int out_size, void* d_ws, size_t ws_size,
                              hipStream_t stream) {
    const float* in = (const float*)d_in[0];
    float* out = (float*)d_out;
    // 16384 wave-tiles, 4 waves per 256-thread block -> 4096 blocks
    hipLaunchKernelGGL(fused_sparsemax_kernel, dim3(4096), dim3(256), 0, stream,
                       in, out);
}